// Round 1
// baseline (1094.253 us; speedup 1.0000x reference)
//
#include <hip/hip_runtime.h>
#include <hip/hip_bf16.h>
#include <stdint.h>

typedef unsigned short u16;
typedef __attribute__((ext_vector_type(8))) short bf16x8;
typedef __attribute__((ext_vector_type(4))) float f32x4;

#define B_    8
#define C_    1024
#define L_    4096
#define R_    32768      // B_*L_
#define SEG   128
#define NSEG  32
#define NROW  16384      // B_*2*1024 scan rows

__device__ __forceinline__ float bf2f(u16 u) {
  union { unsigned int i; float f; } v; v.i = ((unsigned int)u) << 16; return v.f;
}
__device__ __forceinline__ u16 f2bf(float f) {
  union { float f; unsigned int i; } v; v.f = f;
  unsigned int i = v.i + 0x7FFFu + ((v.i >> 16) & 1u);  // RNE
  return (u16)(i >> 16);
}
__device__ __forceinline__ float sigm(float x) { return 1.f / (1.f + __expf(-x)); }

__device__ __forceinline__ void load_lds16(const u16* g, u16* l) {
  __builtin_amdgcn_global_load_lds(
      (const __attribute__((address_space(1))) unsigned int*)g,
      (__attribute__((address_space(3))) unsigned int*)l, 16, 0, 0);
}

// ---------------------------------------------------------------------------
// K0: row-normalize weights -> bf16.  W1n rows: [0..2047]=fore_w, [2048..4095]=back_w
//     (gate row for (d,o) = d*2048+o, hidden = d*2048+1024+o).  W2n = out_w.
__global__ __launch_bounds__(256) void k_wnorm(const float* __restrict__ fw,
                                               const float* __restrict__ bw,
                                               const float* __restrict__ ow,
                                               u16* __restrict__ W1n, u16* __restrict__ W2n) {
  int r = blockIdx.x;           // 0..5119
  const float* src; u16* dst; int K;
  if (r < 4096) { K = 1024;
    src = (r < 2048) ? (fw + (size_t)r * 1024) : (bw + (size_t)(r - 2048) * 1024);
    dst = W1n + (size_t)r * 1024;
  } else { K = 2048;
    src = ow + (size_t)(r - 4096) * 2048;
    dst = W2n + (size_t)(r - 4096) * 2048;
  }
  float ss = 0.f;
  for (int i = threadIdx.x; i < K; i += 256) { float v = src[i]; ss += v * v; }
  for (int off = 32; off >= 1; off >>= 1) ss += __shfl_down(ss, off);
  __shared__ float red[4];
  if ((threadIdx.x & 63) == 0) red[threadIdx.x >> 6] = ss;
  __syncthreads();
  float scale = 1.f / (sqrtf(red[0] + red[1] + red[2] + red[3]) + 1e-4f);
  for (int i = threadIdx.x; i < K; i += 256) dst[i] = f2bf(src[i] * scale);
}

// ---------------------------------------------------------------------------
// K1: x [b][c][l] fp32 -> Xt [(b*L+l)][c] bf16  (LDS-tiled transpose, 64x64)
__global__ __launch_bounds__(256) void k_transpose(const float* __restrict__ x,
                                                   u16* __restrict__ Xt) {
  __shared__ u16 tile[64][66];   // +2 pad -> 33-bank stride, conflict-free
  int l0 = blockIdx.x * 64, c0 = blockIdx.y * 64, b = blockIdx.z;
  int tf = threadIdx.x & 63, tg = threadIdx.x >> 6;
  const float* xp = x + ((size_t)b * C_ + c0) * L_ + l0;
  #pragma unroll
  for (int cc = tg; cc < 64; cc += 4)
    tile[cc][tf] = f2bf(xp[(size_t)cc * L_ + tf]);
  __syncthreads();
  u16* yp = Xt + ((size_t)b * L_ + l0) * C_ + c0;
  #pragma unroll
  for (int ll = tg; ll < 64; ll += 4)
    yp[(size_t)ll * C_ + tf] = tile[tf][ll];
}

// ---------------------------------------------------------------------------
// K2: GEMM1 + fused activation epilogue.
// C[l][o] pair (gate,hidden) per direction.  M=b*l rows of Xt, K=1024.
// Block: 128 l x 64 o, both gate and hidden tiles (B-tile = 64 gate + 64 hidden rows).
// Writes Z=sigmoid(gate), Bv=z*g(hidden) as bf16 planes [b*l][o].
__global__ __launch_bounds__(256) void k_gemm1(const u16* __restrict__ Xt,
                                               const u16* __restrict__ W1n,
                                               u16* __restrict__ Zf, u16* __restrict__ Bf,
                                               u16* __restrict__ Zb, u16* __restrict__ Bb) {
  __shared__ __align__(16) u16 As[128][64];
  __shared__ __align__(16) u16 Bs[128][64];
  int tid = threadIdx.x;
  int lane = tid & 63, wid = tid >> 6;
  int wr = wid >> 1, wc = wid & 1;
  int l15 = lane & 15, khi = lane >> 4;
  size_t m0 = (size_t)blockIdx.x * 128;
  int o0 = blockIdx.y * 64;
  int d  = blockIdx.z;
  int wbase = d * 2048;

  f32x4 accg[4][2], acch[4][2];
  #pragma unroll
  for (int i = 0; i < 4; ++i)
    #pragma unroll
    for (int j = 0; j < 2; ++j) { accg[i][j] = (f32x4){0.f,0.f,0.f,0.f}; acch[i][j] = (f32x4){0.f,0.f,0.f,0.f}; }

  for (int kt = 0; kt < 16; ++kt) {
    int kcol = kt * 64;
    #pragma unroll
    for (int i = 0; i < 4; ++i) {
      int q = i * 256 + tid;            // 0..1023 16B chunks
      int row = q >> 3, c8 = (q & 7) << 3;
      load_lds16(Xt + (m0 + row) * C_ + kcol + c8, &As[row][c8]);
      int brow = wbase + o0 + (row & 63) + ((row >> 6) << 10);  // gate rows then hidden rows
      load_lds16(W1n + (size_t)brow * C_ + kcol + c8, &Bs[row][c8]);
    }
    __syncthreads();
    #pragma unroll
    for (int kc = 0; kc < 2; ++kc) {
      bf16x8 aF[4];
      #pragma unroll
      for (int mf = 0; mf < 4; ++mf)
        aF[mf] = *(const bf16x8*)&As[wr * 64 + mf * 16 + l15][kc * 32 + khi * 8];
      #pragma unroll
      for (int nf = 0; nf < 2; ++nf) {
        bf16x8 bg = *(const bf16x8*)&Bs[wc * 32 + nf * 16 + l15][kc * 32 + khi * 8];
        bf16x8 bh = *(const bf16x8*)&Bs[64 + wc * 32 + nf * 16 + l15][kc * 32 + khi * 8];
        #pragma unroll
        for (int mf = 0; mf < 4; ++mf) {
          accg[mf][nf] = __builtin_amdgcn_mfma_f32_16x16x32_bf16(aF[mf], bg, accg[mf][nf], 0, 0, 0);
          acch[mf][nf] = __builtin_amdgcn_mfma_f32_16x16x32_bf16(aF[mf], bh, acch[mf][nf], 0, 0, 0);
        }
      }
    }
    __syncthreads();
  }

  u16* Zp = d ? Zb : Zf;
  u16* Bp = d ? Bb : Bf;
  #pragma unroll
  for (int mf = 0; mf < 4; ++mf)
    #pragma unroll
    for (int nf = 0; nf < 2; ++nf)
      #pragma unroll
      for (int r = 0; r < 4; ++r) {
        size_t l = m0 + wr * 64 + mf * 16 + khi * 4 + r;      // D row
        int o = o0 + wc * 32 + nf * 16 + l15;                  // D col
        float g  = accg[mf][nf][r];
        float hv = acch[mf][nf][r];
        float z  = sigm(g);
        float ga = (hv >= 0.f) ? (hv + 0.5f) : sigm(hv);
        size_t idx = l * 1024 + o;
        Zp[idx] = f2bf(z);
        Bp[idx] = f2bf(z * ga);
      }
}

// ---------------------------------------------------------------------------
// K3: per-segment composition (A=prod a, B=local scan end), fp32.
__global__ __launch_bounds__(256) void k_scan_seg(const u16* __restrict__ Zf, const u16* __restrict__ Bf,
                                                  const u16* __restrict__ Zb, const u16* __restrict__ Bb,
                                                  float* __restrict__ segA, float* __restrict__ segB) {
  int s = blockIdx.x, og = blockIdx.y, bd = blockIdx.z;
  int b = bd >> 1, d = bd & 1;
  int o = og * 256 + threadIdx.x;
  const u16* Zp = d ? Zb : Zf;
  const u16* Bp = d ? Bb : Bf;
  size_t base = (size_t)b * L_;
  float A = 1.f, Bc = 0.f;
  #pragma unroll 8
  for (int i = 0; i < SEG; ++i) {
    int p = s * SEG + i;
    int l = d ? (L_ - 1 - p) : p;
    size_t idx = (base + l) * 1024 + o;
    float a  = 1.f - bf2f(Zp[idx]);
    float bb = bf2f(Bp[idx]);
    A *= a;
    Bc = __fmaf_rn(a, Bc, bb);
  }
  int row = bd * 1024 + o;
  segA[(size_t)s * NROW + row] = A;
  segB[(size_t)s * NROW + row] = Bc;
}

// K4: prefix over segments -> h at each segment start.
__global__ __launch_bounds__(256) void k_scan_mid(const float* __restrict__ segA,
                                                  const float* __restrict__ segB,
                                                  float* __restrict__ hin) {
  int row = blockIdx.x * 256 + threadIdx.x;
  float h = 0.f;
  #pragma unroll 4
  for (int s = 0; s < NSEG; ++s) {
    hin[(size_t)s * NROW + row] = h;
    h = __fmaf_rn(segA[(size_t)s * NROW + row], h, segB[(size_t)s * NROW + row]);
  }
}

// K5: recompute local scan with correct init, emit Y [b*l][c] bf16, c = d*1024+o.
__global__ __launch_bounds__(256) void k_scan_fin(const u16* __restrict__ Zf, const u16* __restrict__ Bf,
                                                  const u16* __restrict__ Zb, const u16* __restrict__ Bb,
                                                  const float* __restrict__ hin, u16* __restrict__ Y) {
  int s = blockIdx.x, og = blockIdx.y, bd = blockIdx.z;
  int b = bd >> 1, d = bd & 1;
  int o = og * 256 + threadIdx.x;
  const u16* Zp = d ? Zb : Zf;
  const u16* Bp = d ? Bb : Bf;
  size_t base = (size_t)b * L_;
  int row = bd * 1024 + o;
  int c = d * 1024 + o;
  float h = hin[(size_t)s * NROW + row];
  #pragma unroll 8
  for (int i = 0; i < SEG; ++i) {
    int p = s * SEG + i;
    int l = d ? (L_ - 1 - p) : p;
    size_t idx = (base + l) * 1024 + o;
    float a  = 1.f - bf2f(Zp[idx]);
    float bb = bf2f(Bp[idx]);
    h = __fmaf_rn(a, h, bb);
    Y[(base + l) * 2048 + c] = f2bf(h);
  }
}

// ---------------------------------------------------------------------------
// K6: GEMM2: out[b][m][l] = sum_c W2n[m][c] * Y[(b,l)][c].  M=1024, N=32768, K=2048.
__global__ __launch_bounds__(256) void k_gemm2(const u16* __restrict__ W2n,
                                               const u16* __restrict__ Y,
                                               float* __restrict__ out) {
  __shared__ __align__(16) u16 As[128][64];
  __shared__ __align__(16) u16 Bs[128][64];
  int tid = threadIdx.x;
  int lane = tid & 63, wid = tid >> 6;
  int wr = wid >> 1, wc = wid & 1;
  int l15 = lane & 15, khi = lane >> 4;
  size_t n0 = (size_t)blockIdx.x * 128;
  size_t m0 = (size_t)blockIdx.y * 128;

  f32x4 acc[4][4];
  #pragma unroll
  for (int i = 0; i < 4; ++i)
    #pragma unroll
    for (int j = 0; j < 4; ++j) acc[i][j] = (f32x4){0.f,0.f,0.f,0.f};

  for (int kt = 0; kt < 32; ++kt) {
    int kcol = kt * 64;
    #pragma unroll
    for (int i = 0; i < 4; ++i) {
      int q = i * 256 + tid;
      int row = q >> 3, c8 = (q & 7) << 3;
      load_lds16(W2n + (m0 + row) * 2048 + kcol + c8, &As[row][c8]);
      load_lds16(Y   + (n0 + row) * 2048 + kcol + c8, &Bs[row][c8]);
    }
    __syncthreads();
    #pragma unroll
    for (int kc = 0; kc < 2; ++kc) {
      bf16x8 aF[4], bF[4];
      #pragma unroll
      for (int mf = 0; mf < 4; ++mf)
        aF[mf] = *(const bf16x8*)&As[wr * 64 + mf * 16 + l15][kc * 32 + khi * 8];
      #pragma unroll
      for (int nf = 0; nf < 4; ++nf)
        bF[nf] = *(const bf16x8*)&Bs[wc * 64 + nf * 16 + l15][kc * 32 + khi * 8];
      #pragma unroll
      for (int mf = 0; mf < 4; ++mf)
        #pragma unroll
        for (int nf = 0; nf < 4; ++nf)
          acc[mf][nf] = __builtin_amdgcn_mfma_f32_16x16x32_bf16(aF[mf], bF[nf], acc[mf][nf], 0, 0, 0);
    }
    __syncthreads();
  }

  int b = (int)(n0 >> 12);
  int lbase = (int)(n0 & 4095);
  #pragma unroll
  for (int mf = 0; mf < 4; ++mf)
    #pragma unroll
    for (int nf = 0; nf < 4; ++nf)
      #pragma unroll
      for (int r = 0; r < 4; ++r) {
        int m = (int)m0 + wr * 64 + mf * 16 + khi * 4 + r;  // D row = M
        int l = lbase + wc * 64 + nf * 16 + l15;            // D col = N
        out[((size_t)b * 1024 + m) * 4096 + l] = acc[mf][nf][r];
      }
}

// ---------------------------------------------------------------------------
extern "C" void kernel_launch(void* const* d_in, const int* in_sizes, int n_in,
                              void* d_out, int out_size, void* d_ws, size_t ws_size,
                              hipStream_t stream) {
  (void)in_sizes; (void)n_in; (void)out_size; (void)ws_size;
  const float* x  = (const float*)d_in[0];
  const float* fw = (const float*)d_in[1];
  const float* bw = (const float*)d_in[2];
  const float* ow = (const float*)d_in[3];
  float* out = (float*)d_out;
  char* ws = (char*)d_ws;

  // workspace layout (bytes); Y aliases Xt region (Xt dead after k_gemm1)
  u16* Zf  = (u16*)(ws + 0);                       //  64 MiB
  u16* Bfp = (u16*)(ws + 67108864ull);             //  64 MiB
  u16* Y   = (u16*)(ws + 134217728ull);            // 128 MiB
  u16* Xt  = (u16*)(ws + 134217728ull);            //  64 MiB (alias of Y, dead before K5)
  u16* W1n = (u16*)(ws + 268435456ull);            //   8 MiB
  u16* W2n = (u16*)(ws + 276824064ull);            //   4 MiB
  float* segA = (float*)(ws + 281018368ull);       //   2 MiB
  float* segB = (float*)(ws + 283115520ull);       //   2 MiB
  float* hin  = (float*)(ws + 285212672ull);       //   2 MiB  (end ~274 MiB)
  // back-direction z/b planes live in d_out (exactly 2 x 64 MiB), dead before K6 writes
  u16* Zb = (u16*)d_out;
  u16* Bb = (u16*)((char*)d_out + 67108864ull);

  k_wnorm    <<<dim3(5120),      dim3(256), 0, stream>>>(fw, bw, ow, W1n, W2n);
  k_transpose<<<dim3(64, 16, 8), dim3(256), 0, stream>>>(x, Xt);
  k_gemm1    <<<dim3(256, 16, 2),dim3(256), 0, stream>>>(Xt, W1n, Zf, Bfp, Zb, Bb);
  k_scan_seg <<<dim3(NSEG, 4, 16), dim3(256), 0, stream>>>(Zf, Bfp, Zb, Bb, segA, segB);
  k_scan_mid <<<dim3(64),        dim3(256), 0, stream>>>(segA, segB, hin);
  k_scan_fin <<<dim3(NSEG, 4, 16), dim3(256), 0, stream>>>(Zf, Bfp, Zb, Bb, hin, Y);
  k_gemm2    <<<dim3(256, 8),    dim3(256), 0, stream>>>(W2n, Y, out);
}

// Round 2
// 893.877 us; speedup vs baseline: 1.2242x; 1.2242x over previous
//
#include <hip/hip_runtime.h>
#include <hip/hip_bf16.h>
#include <stdint.h>

typedef unsigned short u16;
typedef __attribute__((ext_vector_type(8))) short bf16x8;
typedef __attribute__((ext_vector_type(4))) float f32x4;

#define B_    8
#define C_    1024
#define L_    4096
#define SEG   128
#define NSEG  32
#define NROW  16384      // B_*2*1024 scan rows

__device__ __forceinline__ float bf2f(u16 u) {
  union { unsigned int i; float f; } v; v.i = ((unsigned int)u) << 16; return v.f;
}
__device__ __forceinline__ u16 f2bf(float f) {
  union { float f; unsigned int i; } v; v.f = f;
  unsigned int i = v.i + 0x7FFFu + ((v.i >> 16) & 1u);  // RNE
  return (u16)(i >> 16);
}
__device__ __forceinline__ float sigm(float x) { return 1.f / (1.f + __expf(-x)); }

__device__ __forceinline__ void load_lds16(const u16* g, u16* l) {
  __builtin_amdgcn_global_load_lds(
      (const __attribute__((address_space(1))) unsigned int*)g,
      (__attribute__((address_space(3))) unsigned int*)l, 16, 0, 0);
}

// ---------------------------------------------------------------------------
// 8-phase-class GEMM building blocks (BK=32, ring-4 LDS, packed-swizzled tiles)
//
// LDS tile layout per operand slot: logical (m in [0,256), k in [0,32)) u16
//   lds_row = m>>1 (128 rows of 128 B), logical bytecol = (m&1)*64 + k*2
//   stored bytecol = logical bytecol ^ ((lds_row&7)<<4)   [T2 swizzle]
// Stage writes LINEAR LDS (global_load_lds constraint); the global SOURCE
// address is inverse-swizzled so the swizzled read pattern sees correct data.

__device__ __forceinline__ void stage_op(const u16* __restrict__ gsrc, int ldk,
                                         u16* lds, int t) {
  #pragma unroll
  for (int j = 0; j < 2; ++j) {
    int off16 = j * 512 + t;                 // 16B chunk 0..1023 (16 KiB slot)
    int lr = off16 >> 3;                     // lds row 0..127
    int bcl = ((t & 7) << 4) ^ ((lr & 7) << 4);  // logical bytecol
    int m  = (lr << 1) + (bcl >> 6);
    int ku = (bcl & 63) >> 1;
    load_lds16(gsrc + (size_t)m * ldk + ku, lds + off16 * 8);
  }
}

__device__ __forceinline__ bf16x8 frag_ld(const u16* lds, int m, int khi) {
  int lr = m >> 1;
  int bc = (((m & 1) << 6) | (khi << 4)) ^ ((lr & 7) << 4);
  return *(const bf16x8*)((const char*)lds + lr * 128 + bc);
}

// EPI 0: gemm1 (A=Xt[32768][1024], B=W1n[4096][1024]) -> z / g(h) bf16 planes
// EPI 1: gemm2 (A=W2n[1024][2048], B=Y[32768][2048]) -> out fp32 [b][m][l]
template<int LDK, int NT, int EPI>
__global__ __launch_bounds__(512, 2) void gemm8p(
    const u16* __restrict__ A, const u16* __restrict__ Bm,
    u16* __restrict__ P0, u16* __restrict__ P1,
    u16* __restrict__ P2, u16* __restrict__ P3,
    float* __restrict__ Fout) {
  __shared__ __align__(16) u16 lA[4][8192];
  __shared__ __align__(16) u16 lB[4][8192];

  int tid = threadIdx.x;
  int lane = tid & 63, wid = tid >> 6;
  int wr = wid >> 2, wc = wid & 3;              // 2 (M) x 4 (N) waves
  int l15 = lane & 15, khi = lane >> 4;

  int bid = blockIdx.x, tm, tn;
  if constexpr (EPI == 0) { int s = (bid & 7) * 256 + (bid >> 3); tm = s >> 4; tn = s & 15; }
  else                    { int s = (bid & 7) * 64  + (bid >> 3); tn = s >> 2; tm = s & 3; }
  size_t m0 = (size_t)tm * 256, n0 = (size_t)tn * 256;
  const u16* Ag = A  + m0 * LDK;
  const u16* Bg = Bm + n0 * LDK;

  f32x4 acc[8][4];
  #pragma unroll
  for (int i = 0; i < 8; ++i)
    #pragma unroll
    for (int j = 0; j < 4; ++j) acc[i][j] = (f32x4){0.f, 0.f, 0.f, 0.f};

  // prologue: stage tiles 0,1,2 (order A,B per tile); tile0 landed, 1&2 in flight
  #pragma unroll
  for (int p = 0; p < 3; ++p) {
    stage_op(Ag + p * 32, LDK, lA[p], tid);
    stage_op(Bg + p * 32, LDK, lB[p], tid);
  }
  asm volatile("s_waitcnt vmcnt(8)\n" ::: "memory");
  asm volatile("s_barrier\n" ::: "memory");

  const int rA = wr * 128 + l15;
  const int rB = wc * 64 + l15;

  for (int kk = 0; kk < NT; ++kk) {
    const u16* sA = lA[kk & 3];
    const u16* sB = lB[kk & 3];
    const bool st = (kk + 3 < NT);

    // ---- phase 0: read A(mf0-3) + all B frags; stage A of tile kk+3 ----
    bf16x8 a0[4], b0[4];
    #pragma unroll
    for (int mf = 0; mf < 4; ++mf) a0[mf] = frag_ld(sA, rA + mf * 16, khi);
    #pragma unroll
    for (int nf = 0; nf < 4; ++nf) b0[nf] = frag_ld(sB, rB + nf * 16, khi);
    if (st) stage_op(Ag + (kk + 3) * 32, LDK, lA[(kk + 3) & 3], tid);
    asm volatile("s_barrier\n" ::: "memory");
    __builtin_amdgcn_s_setprio(1);
    #pragma unroll
    for (int mf = 0; mf < 4; ++mf)
      #pragma unroll
      for (int nf = 0; nf < 4; ++nf)
        acc[mf][nf] = __builtin_amdgcn_mfma_f32_16x16x32_bf16(a0[mf], b0[nf], acc[mf][nf], 0, 0, 0);
    __builtin_amdgcn_s_setprio(0);
    asm volatile("s_barrier\n" ::: "memory");

    // ---- phase 1: read A(mf4-7); stage B of tile kk+3 ----
    bf16x8 a1[4];
    #pragma unroll
    for (int mf = 0; mf < 4; ++mf) a1[mf] = frag_ld(sA, rA + 64 + mf * 16, khi);
    if (st) stage_op(Bg + (kk + 3) * 32, LDK, lB[(kk + 3) & 3], tid);
    asm volatile("s_barrier\n" ::: "memory");
    __builtin_amdgcn_s_setprio(1);
    #pragma unroll
    for (int mf = 0; mf < 4; ++mf)
      #pragma unroll
      for (int nf = 0; nf < 4; ++nf)
        acc[4 + mf][nf] = __builtin_amdgcn_mfma_f32_16x16x32_bf16(a1[mf], b0[nf], acc[4 + mf][nf], 0, 0, 0);
    __builtin_amdgcn_s_setprio(0);
    // counted per-K-tile wait (T4): next group needs tile kk+1 landed;
    // tiles kk+2, kk+3 stay in flight (4 instr each per wave) -> vmcnt(8)
    if (kk < NT - 3)       { asm volatile("s_waitcnt vmcnt(8)\n" ::: "memory"); }
    else if (kk == NT - 3) { asm volatile("s_waitcnt vmcnt(4)\n" ::: "memory"); }
    else if (kk == NT - 2) { asm volatile("s_waitcnt vmcnt(0)\n" ::: "memory"); }
    asm volatile("s_barrier\n" ::: "memory");
  }

  // epilogue: m_local = wr*128 + i*16 + khi*4 + r ; n_local = wc*64 + nf*16 + l15
  if constexpr (EPI == 0) {
    u16* plane = (tn < 4) ? P0 : (tn < 8) ? P1 : (tn < 12) ? P2 : P3;
    const bool gate = ((tn >> 2) & 1) == 0;
    const int obase = (tn & 3) * 256;
    #pragma unroll
    for (int i = 0; i < 8; ++i)
      #pragma unroll
      for (int nf = 0; nf < 4; ++nf)
        #pragma unroll
        for (int r = 0; r < 4; ++r) {
          size_t l = m0 + wr * 128 + i * 16 + khi * 4 + r;
          int o = obase + wc * 64 + nf * 16 + l15;
          float v = acc[i][nf][r];
          float res = gate ? sigm(v) : ((v >= 0.f) ? v + 0.5f : sigm(v));
          plane[l * 1024 + o] = f2bf(res);
        }
  } else {
    int b  = (int)(n0 >> 12);
    int lb = (int)(n0 & 4095);
    #pragma unroll
    for (int i = 0; i < 8; ++i)
      #pragma unroll
      for (int nf = 0; nf < 4; ++nf)
        #pragma unroll
        for (int r = 0; r < 4; ++r) {
          int m = (int)m0 + wr * 128 + i * 16 + khi * 4 + r;
          int l = lb + wc * 64 + nf * 16 + l15;
          Fout[((size_t)b * 1024 + m) * 4096 + l] = acc[i][nf][r];
        }
  }
}

// ---------------------------------------------------------------------------
// K0: row-normalize weights -> bf16.  W1n rows: [0..2047]=fore_w, [2048..4095]=back_w
__global__ __launch_bounds__(256) void k_wnorm(const float* __restrict__ fw,
                                               const float* __restrict__ bw,
                                               const float* __restrict__ ow,
                                               u16* __restrict__ W1n, u16* __restrict__ W2n) {
  int r = blockIdx.x;           // 0..5119
  const float* src; u16* dst; int K;
  if (r < 4096) { K = 1024;
    src = (r < 2048) ? (fw + (size_t)r * 1024) : (bw + (size_t)(r - 2048) * 1024);
    dst = W1n + (size_t)r * 1024;
  } else { K = 2048;
    src = ow + (size_t)(r - 4096) * 2048;
    dst = W2n + (size_t)(r - 4096) * 2048;
  }
  float ss = 0.f;
  for (int i = threadIdx.x; i < K; i += 256) { float v = src[i]; ss += v * v; }
  for (int off = 32; off >= 1; off >>= 1) ss += __shfl_down(ss, off);
  __shared__ float red[4];
  if ((threadIdx.x & 63) == 0) red[threadIdx.x >> 6] = ss;
  __syncthreads();
  float scale = 1.f / (sqrtf(red[0] + red[1] + red[2] + red[3]) + 1e-4f);
  for (int i = threadIdx.x; i < K; i += 256) dst[i] = f2bf(src[i] * scale);
}

// ---------------------------------------------------------------------------
// K1: x [b][c][l] fp32 -> Xt [(b*L+l)][c] bf16  (LDS-tiled transpose, 64x64)
__global__ __launch_bounds__(256) void k_transpose(const float* __restrict__ x,
                                                   u16* __restrict__ Xt) {
  __shared__ u16 tile[64][66];
  int l0 = blockIdx.x * 64, c0 = blockIdx.y * 64, b = blockIdx.z;
  int tf = threadIdx.x & 63, tg = threadIdx.x >> 6;
  const float* xp = x + ((size_t)b * C_ + c0) * L_ + l0;
  #pragma unroll
  for (int cc = tg; cc < 64; cc += 4)
    tile[cc][tf] = f2bf(xp[(size_t)cc * L_ + tf]);
  __syncthreads();
  u16* yp = Xt + ((size_t)b * L_ + l0) * C_ + c0;
  #pragma unroll
  for (int ll = tg; ll < 64; ll += 4)
    yp[(size_t)ll * C_ + tf] = tile[tf][ll];
}

// ---------------------------------------------------------------------------
// K3: per-segment composition (A=prod a, B=local scan end), fp32.
// planes: Z = sigmoid(gate), H = g(hidden);  a = 1-z, b = z*h
__global__ __launch_bounds__(256) void k_scan_seg(const u16* __restrict__ Zf, const u16* __restrict__ Hf,
                                                  const u16* __restrict__ Zb, const u16* __restrict__ Hb,
                                                  float* __restrict__ segA, float* __restrict__ segB) {
  int s = blockIdx.x, og = blockIdx.y, bd = blockIdx.z;
  int b = bd >> 1, d = bd & 1;
  int o = og * 256 + threadIdx.x;
  const u16* Zp = d ? Zb : Zf;
  const u16* Hp = d ? Hb : Hf;
  size_t base = (size_t)b * L_;
  float A = 1.f, Bc = 0.f;
  #pragma unroll 8
  for (int i = 0; i < SEG; ++i) {
    int p = s * SEG + i;
    int l = d ? (L_ - 1 - p) : p;
    size_t idx = (base + l) * 1024 + o;
    float z  = bf2f(Zp[idx]);
    float a  = 1.f - z;
    float bb = z * bf2f(Hp[idx]);
    A *= a;
    Bc = __fmaf_rn(a, Bc, bb);
  }
  int row = bd * 1024 + o;
  segA[(size_t)s * NROW + row] = A;
  segB[(size_t)s * NROW + row] = Bc;
}

// K4: prefix over segments -> h at each segment start.
__global__ __launch_bounds__(256) void k_scan_mid(const float* __restrict__ segA,
                                                  const float* __restrict__ segB,
                                                  float* __restrict__ hin) {
  int row = blockIdx.x * 256 + threadIdx.x;
  float h = 0.f;
  #pragma unroll 4
  for (int s = 0; s < NSEG; ++s) {
    hin[(size_t)s * NROW + row] = h;
    h = __fmaf_rn(segA[(size_t)s * NROW + row], h, segB[(size_t)s * NROW + row]);
  }
}

// K5: recompute local scan with correct init, emit Y [b*l][c] bf16, c = d*1024+o.
__global__ __launch_bounds__(256) void k_scan_fin(const u16* __restrict__ Zf, const u16* __restrict__ Hf,
                                                  const u16* __restrict__ Zb, const u16* __restrict__ Hb,
                                                  const float* __restrict__ hin, u16* __restrict__ Y) {
  int s = blockIdx.x, og = blockIdx.y, bd = blockIdx.z;
  int b = bd >> 1, d = bd & 1;
  int o = og * 256 + threadIdx.x;
  const u16* Zp = d ? Zb : Zf;
  const u16* Hp = d ? Hb : Hf;
  size_t base = (size_t)b * L_;
  int row = bd * 1024 + o;
  int c = d * 1024 + o;
  float h = hin[(size_t)s * NROW + row];
  #pragma unroll 8
  for (int i = 0; i < SEG; ++i) {
    int p = s * SEG + i;
    int l = d ? (L_ - 1 - p) : p;
    size_t idx = (base + l) * 1024 + o;
    float z  = bf2f(Zp[idx]);
    float a  = 1.f - z;
    float bb = z * bf2f(Hp[idx]);
    h = __fmaf_rn(a, h, bb);
    Y[(base + l) * 2048 + c] = f2bf(h);
  }
}

// ---------------------------------------------------------------------------
extern "C" void kernel_launch(void* const* d_in, const int* in_sizes, int n_in,
                              void* d_out, int out_size, void* d_ws, size_t ws_size,
                              hipStream_t stream) {
  (void)in_sizes; (void)n_in; (void)out_size; (void)ws_size;
  const float* x  = (const float*)d_in[0];
  const float* fw = (const float*)d_in[1];
  const float* bw = (const float*)d_in[2];
  const float* ow = (const float*)d_in[3];
  float* out = (float*)d_out;
  char* ws = (char*)d_ws;

  // workspace layout (bytes); Y aliases Xt region (Xt dead after gemm1)
  u16* Zf  = (u16*)(ws + 0);                       //  64 MiB
  u16* Hf  = (u16*)(ws + 67108864ull);             //  64 MiB
  u16* Y   = (u16*)(ws + 134217728ull);            // 128 MiB
  u16* Xt  = (u16*)(ws + 134217728ull);            //  64 MiB (alias of Y, dead before K5)
  u16* W1n = (u16*)(ws + 268435456ull);            //   8 MiB
  u16* W2n = (u16*)(ws + 276824064ull);            //   4 MiB
  float* segA = (float*)(ws + 281018368ull);       //   2 MiB
  float* segB = (float*)(ws + 283115520ull);       //   2 MiB
  float* hin  = (float*)(ws + 285212672ull);       //   2 MiB
  // back-direction z/h planes live in d_out (2 x 64 MiB), dead before gemm2 writes
  u16* Zb = (u16*)d_out;
  u16* Hb = (u16*)((char*)d_out + 67108864ull);

  k_wnorm    <<<dim3(5120),      dim3(256), 0, stream>>>(fw, bw, ow, W1n, W2n);
  k_transpose<<<dim3(64, 16, 8), dim3(256), 0, stream>>>(x, Xt);
  gemm8p<1024, 32, 0><<<dim3(2048), dim3(512), 0, stream>>>(Xt, W1n, Zf, Hf, Zb, Hb, nullptr);
  k_scan_seg <<<dim3(NSEG, 4, 16), dim3(256), 0, stream>>>(Zf, Hf, Zb, Hb, segA, segB);
  k_scan_mid <<<dim3(64),        dim3(256), 0, stream>>>(segA, segB, hin);
  k_scan_fin <<<dim3(NSEG, 4, 16), dim3(256), 0, stream>>>(Zf, Hf, Zb, Hb, hin, Y);
  gemm8p<2048, 64, 1><<<dim3(512),  dim3(512), 0, stream>>>(W2n, Y, nullptr, nullptr, nullptr, nullptr, out);
}

// Round 3
// 861.698 us; speedup vs baseline: 1.2699x; 1.0373x over previous
//
#include <hip/hip_runtime.h>
#include <hip/hip_bf16.h>
#include <stdint.h>

typedef unsigned short u16;
typedef __attribute__((ext_vector_type(8))) short bf16x8;
typedef __attribute__((ext_vector_type(4))) float f32x4;

#define B_    8
#define C_    1024
#define L_    4096
#define SEG   128
#define NSEG  32
#define NROW  16384      // B_*2*1024 scan rows

__device__ __forceinline__ float bf2f(u16 u) {
  union { unsigned int i; float f; } v; v.i = ((unsigned int)u) << 16; return v.f;
}
__device__ __forceinline__ u16 f2bf(float f) {
  union { float f; unsigned int i; } v; v.f = f;
  unsigned int i = v.i + 0x7FFFu + ((v.i >> 16) & 1u);  // RNE
  return (u16)(i >> 16);
}
__device__ __forceinline__ float sigm(float x) { return 1.f / (1.f + __expf(-x)); }

__device__ __forceinline__ void load_lds16(const u16* g, u16* l) {
  __builtin_amdgcn_global_load_lds(
      (const __attribute__((address_space(1))) unsigned int*)g,
      (__attribute__((address_space(3))) unsigned int*)l, 16, 0, 0);
}

// ---------------------------------------------------------------------------
// Ring-4 BK=32 GEMM, 256x256 tile, 8 waves (2Mx4N), XOR-swizzled packed LDS.
// Identical sync structure to R2 (verified); addressing fully hoisted:
// frag reads = ds_read_b128 base+imm, slot compile-time via x4 unroll.
template<int LDK, int NT, int EPI>
__global__ __launch_bounds__(512, 2) void gemm8p(
    const u16* __restrict__ A, const u16* __restrict__ Bm,
    u16* __restrict__ P0, u16* __restrict__ P1,
    u16* __restrict__ P2, u16* __restrict__ P3,
    float* __restrict__ Fout) {
  __shared__ __align__(16) u16 lA[4][8192];
  __shared__ __align__(16) u16 lB[4][8192];

  int tid = threadIdx.x;
  int lane = tid & 63, wid = tid >> 6;
  int wr = wid >> 2, wc = wid & 3;              // 2 (M) x 4 (N) waves
  int l15 = lane & 15, khi = lane >> 4;

  int bid = blockIdx.x, tm, tn;
  if constexpr (EPI == 0) { int s = (bid & 7) * 256 + (bid >> 3); tm = s >> 4; tn = s & 15; }
  else                    { int s = (bid & 7) * 64  + (bid >> 3); tn = s >> 2; tm = s & 3; }
  size_t m0 = (size_t)tm * 256, n0 = (size_t)tn * 256;
  const u16* Ag = A  + m0 * LDK;
  const u16* Bg = Bm + n0 * LDK;

  // ---- stage source pointers (per-thread, inverse-swizzled), bumped per group
  const u16* pA[2]; const u16* pB[2]; int dof[2];
  #pragma unroll
  for (int j = 0; j < 2; ++j) {
    int off16 = j * 512 + tid;
    int lr  = off16 >> 3;
    int bcl = ((tid & 7) << 4) ^ ((lr & 7) << 4);
    int m   = (lr << 1) + (bcl >> 6);
    int ku  = (bcl & 63) >> 1;
    pA[j] = Ag + (size_t)m * LDK + ku;
    pB[j] = Bg + (size_t)m * LDK + ku;
    dof[j] = off16 * 8;
  }

  // ---- frag read bases (swizzle algebra: slot/mf offsets are constants)
  int lrA = (wr * 128 + l15) >> 1;
  int bcA = (((l15 & 1) << 6) | (khi << 4)) ^ ((lrA & 7) << 4);
  const char* baseA = (const char*)&lA[0][0] + lrA * 128 + bcA;
  int lrB = (wc * 64 + l15) >> 1;
  int bcB = (((l15 & 1) << 6) | (khi << 4)) ^ ((lrB & 7) << 4);
  const char* baseB = (const char*)&lB[0][0] + lrB * 128 + bcB;

  f32x4 acc[8][4];
  #pragma unroll
  for (int i = 0; i < 8; ++i)
    #pragma unroll
    for (int j = 0; j < 4; ++j) acc[i][j] = (f32x4){0.f, 0.f, 0.f, 0.f};

  // prologue: stage tiles 0,1,2 (A,B per tile); wait tile0 landed
  #pragma unroll
  for (int p = 0; p < 3; ++p) {
    load_lds16(pA[0] + p * 32, &lA[p][dof[0]]);
    load_lds16(pA[1] + p * 32, &lA[p][dof[1]]);
    load_lds16(pB[0] + p * 32, &lB[p][dof[0]]);
    load_lds16(pB[1] + p * 32, &lB[p][dof[1]]);
  }
  asm volatile("s_waitcnt vmcnt(8)\n" ::: "memory");
  asm volatile("s_barrier\n" ::: "memory");

#define FRA(S, MF) (*(const bf16x8*)(baseA + (S) * 16384 + (MF) * 1024))
#define FRB(S, NF) (*(const bf16x8*)(baseB + (S) * 16384 + (NF) * 1024))

  for (int kt0 = 0; kt0 < NT; kt0 += 4) {
    #pragma unroll
    for (int u = 0; u < 4; ++u) {
      const int kt = kt0 + u;
      constexpr int S3_[4] = {3, 0, 1, 2};
      const int S3 = S3_[u];                    // (u+3)&3, compile-time
      const bool st = (kt + 3 < NT);

      // ---- phase 0: read A(mf0-3) + all B frags; stage A of tile kt+3 ----
      bf16x8 a0[4], b0[4];
      #pragma unroll
      for (int mf = 0; mf < 4; ++mf) a0[mf] = FRA(u, mf);
      #pragma unroll
      for (int nf = 0; nf < 4; ++nf) b0[nf] = FRB(u, nf);
      if (st) {
        load_lds16(pA[0] + (u + 3) * 32, &lA[S3][dof[0]]);
        load_lds16(pA[1] + (u + 3) * 32, &lA[S3][dof[1]]);
      }
      asm volatile("s_barrier\n" ::: "memory");
      __builtin_amdgcn_s_setprio(1);
      #pragma unroll
      for (int mf = 0; mf < 4; ++mf)
        #pragma unroll
        for (int nf = 0; nf < 4; ++nf)
          acc[mf][nf] = __builtin_amdgcn_mfma_f32_16x16x32_bf16(a0[mf], b0[nf], acc[mf][nf], 0, 0, 0);
      __builtin_amdgcn_s_setprio(0);
      asm volatile("s_barrier\n" ::: "memory");

      // ---- phase 1: read A(mf4-7); stage B of tile kt+3 ----
      bf16x8 a1[4];
      #pragma unroll
      for (int mf = 0; mf < 4; ++mf) a1[mf] = FRA(u, 4 + mf);
      if (st) {
        load_lds16(pB[0] + (u + 3) * 32, &lB[S3][dof[0]]);
        load_lds16(pB[1] + (u + 3) * 32, &lB[S3][dof[1]]);
      }
      asm volatile("s_barrier\n" ::: "memory");
      __builtin_amdgcn_s_setprio(1);
      #pragma unroll
      for (int mf = 0; mf < 4; ++mf)
        #pragma unroll
        for (int nf = 0; nf < 4; ++nf)
          acc[4 + mf][nf] = __builtin_amdgcn_mfma_f32_16x16x32_bf16(a1[mf], b0[nf], acc[4 + mf][nf], 0, 0, 0);
      __builtin_amdgcn_s_setprio(0);
      // counted per-K-tile wait (T4): tile kt+1 landed; kt+2,kt+3 in flight
      if (kt < NT - 3)       { asm volatile("s_waitcnt vmcnt(8)\n" ::: "memory"); }
      else if (kt == NT - 3) { asm volatile("s_waitcnt vmcnt(4)\n" ::: "memory"); }
      else if (kt == NT - 2) { asm volatile("s_waitcnt vmcnt(0)\n" ::: "memory"); }
      asm volatile("s_barrier\n" ::: "memory");
    }
    pA[0] += 128; pA[1] += 128; pB[0] += 128; pB[1] += 128;
  }
#undef FRA
#undef FRB

  // epilogue: m_local = wr*128 + i*16 + khi*4 + r ; n_local = wc*64 + nf*16 + l15
  if constexpr (EPI == 0) {
    u16* plane = (tn < 4) ? P0 : (tn < 8) ? P1 : (tn < 12) ? P2 : P3;
    const bool gate = ((tn >> 2) & 1) == 0;
    const int obase = (tn & 3) * 256;
    #pragma unroll
    for (int i = 0; i < 8; ++i)
      #pragma unroll
      for (int nf = 0; nf < 4; ++nf)
        #pragma unroll
        for (int r = 0; r < 4; ++r) {
          size_t l = m0 + wr * 128 + i * 16 + khi * 4 + r;
          int o = obase + wc * 64 + nf * 16 + l15;
          float v = acc[i][nf][r];
          float res = gate ? sigm(v) : ((v >= 0.f) ? v + 0.5f : sigm(v));
          plane[l * 1024 + o] = f2bf(res);
        }
  } else {
    int b  = (int)(n0 >> 12);
    int lb = (int)(n0 & 4095);
    #pragma unroll
    for (int i = 0; i < 8; ++i)
      #pragma unroll
      for (int nf = 0; nf < 4; ++nf)
        #pragma unroll
        for (int r = 0; r < 4; ++r) {
          int m = (int)m0 + wr * 128 + i * 16 + khi * 4 + r;
          int l = lb + wc * 64 + nf * 16 + l15;
          Fout[((size_t)b * 1024 + m) * 4096 + l] = acc[i][nf][r];
        }
  }
}

// ---------------------------------------------------------------------------
// K0: row-normalize weights -> bf16.
__global__ __launch_bounds__(256) void k_wnorm(const float* __restrict__ fw,
                                               const float* __restrict__ bw,
                                               const float* __restrict__ ow,
                                               u16* __restrict__ W1n, u16* __restrict__ W2n) {
  int r = blockIdx.x;           // 0..5119
  const float* src; u16* dst; int K;
  if (r < 4096) { K = 1024;
    src = (r < 2048) ? (fw + (size_t)r * 1024) : (bw + (size_t)(r - 2048) * 1024);
    dst = W1n + (size_t)r * 1024;
  } else { K = 2048;
    src = ow + (size_t)(r - 4096) * 2048;
    dst = W2n + (size_t)(r - 4096) * 2048;
  }
  float ss = 0.f;
  for (int i = threadIdx.x; i < K; i += 256) { float v = src[i]; ss += v * v; }
  for (int off = 32; off >= 1; off >>= 1) ss += __shfl_down(ss, off);
  __shared__ float red[4];
  if ((threadIdx.x & 63) == 0) red[threadIdx.x >> 6] = ss;
  __syncthreads();
  float scale = 1.f / (sqrtf(red[0] + red[1] + red[2] + red[3]) + 1e-4f);
  for (int i = threadIdx.x; i < K; i += 256) dst[i] = f2bf(src[i] * scale);
}

// ---------------------------------------------------------------------------
// K1: x [b][c][l] fp32 -> Xt [(b*L+l)][c] bf16
__global__ __launch_bounds__(256) void k_transpose(const float* __restrict__ x,
                                                   u16* __restrict__ Xt) {
  __shared__ u16 tile[64][66];
  int l0 = blockIdx.x * 64, c0 = blockIdx.y * 64, b = blockIdx.z;
  int tf = threadIdx.x & 63, tg = threadIdx.x >> 6;
  const float* xp = x + ((size_t)b * C_ + c0) * L_ + l0;
  #pragma unroll
  for (int cc = tg; cc < 64; cc += 4)
    tile[cc][tf] = f2bf(xp[(size_t)cc * L_ + tf]);
  __syncthreads();
  u16* yp = Xt + ((size_t)b * L_ + l0) * C_ + c0;
  #pragma unroll
  for (int ll = tg; ll < 64; ll += 4)
    yp[(size_t)ll * C_ + tf] = tile[tf][ll];
}

// ---------------------------------------------------------------------------
// K3: per-segment composition, 4 channels/thread (ushort4 loads).
__global__ __launch_bounds__(256) void k_scan_seg(const u16* __restrict__ Zf, const u16* __restrict__ Hf,
                                                  const u16* __restrict__ Zb, const u16* __restrict__ Hb,
                                                  float* __restrict__ segA, float* __restrict__ segB) {
  int s = blockIdx.x, bd = blockIdx.z;
  int b = bd >> 1, d = bd & 1;
  int tid = threadIdx.x;
  const ushort4* Zp = (const ushort4*)(d ? Zb : Zf);
  const ushort4* Hp = (const ushort4*)(d ? Hb : Hf);
  size_t base = (size_t)b * L_;
  float A[4] = {1.f, 1.f, 1.f, 1.f}, Bc[4] = {0.f, 0.f, 0.f, 0.f};
  #pragma unroll 4
  for (int i = 0; i < SEG; ++i) {
    int p = s * SEG + i;
    int l = d ? (L_ - 1 - p) : p;
    size_t idx = (base + l) * 256 + tid;
    ushort4 z4 = Zp[idx], h4 = Hp[idx];
    const u16* zc = (const u16*)&z4; const u16* hc = (const u16*)&h4;
    #pragma unroll
    for (int c = 0; c < 4; ++c) {
      float z = bf2f(zc[c]);
      float a = 1.f - z;
      A[c] *= a;
      Bc[c] = __fmaf_rn(a, Bc[c], z * bf2f(hc[c]));
    }
  }
  float4* sA = (float4*)(segA + (size_t)s * NROW + bd * 1024);
  float4* sB = (float4*)(segB + (size_t)s * NROW + bd * 1024);
  sA[tid] = (float4){A[0], A[1], A[2], A[3]};
  sB[tid] = (float4){Bc[0], Bc[1], Bc[2], Bc[3]};
}

// K4: prefix over segments (4 rows/thread, float4).
__global__ __launch_bounds__(256) void k_scan_mid(const float* __restrict__ segA,
                                                  const float* __restrict__ segB,
                                                  float* __restrict__ hin) {
  int t = blockIdx.x * 256 + threadIdx.x;     // 0..4095
  const float4* A4 = (const float4*)segA;
  const float4* B4 = (const float4*)segB;
  float4* H4 = (float4*)hin;
  float4 h = {0.f, 0.f, 0.f, 0.f};
  #pragma unroll 4
  for (int s = 0; s < NSEG; ++s) {
    H4[s * 4096 + t] = h;
    float4 a = A4[s * 4096 + t], b = B4[s * 4096 + t];
    h.x = __fmaf_rn(a.x, h.x, b.x); h.y = __fmaf_rn(a.y, h.y, b.y);
    h.z = __fmaf_rn(a.z, h.z, b.z); h.w = __fmaf_rn(a.w, h.w, b.w);
  }
}

// K5: recompute local scan, emit Y [b*l][c] bf16, 4 channels/thread.
__global__ __launch_bounds__(256) void k_scan_fin(const u16* __restrict__ Zf, const u16* __restrict__ Hf,
                                                  const u16* __restrict__ Zb, const u16* __restrict__ Hb,
                                                  const float* __restrict__ hin, u16* __restrict__ Y) {
  int s = blockIdx.x, bd = blockIdx.z;
  int b = bd >> 1, d = bd & 1;
  int tid = threadIdx.x;
  const ushort4* Zp = (const ushort4*)(d ? Zb : Zf);
  const ushort4* Hp = (const ushort4*)(d ? Hb : Hf);
  size_t base = (size_t)b * L_;
  float4 h0 = ((const float4*)hin)[(size_t)s * 4096 + bd * 256 + tid];
  float h[4] = {h0.x, h0.y, h0.z, h0.w};
  ushort4* Y4 = (ushort4*)Y;
  #pragma unroll 4
  for (int i = 0; i < SEG; ++i) {
    int p = s * SEG + i;
    int l = d ? (L_ - 1 - p) : p;
    size_t idx = (base + l) * 256 + tid;
    ushort4 z4 = Zp[idx], h4 = Hp[idx];
    const u16* zc = (const u16*)&z4; const u16* hc = (const u16*)&h4;
    ushort4 o4;
    u16* oc = (u16*)&o4;
    #pragma unroll
    for (int c = 0; c < 4; ++c) {
      float z = bf2f(zc[c]);
      float a = 1.f - z;
      h[c] = __fmaf_rn(a, h[c], z * bf2f(hc[c]));
      oc[c] = f2bf(h[c]);
    }
    Y4[(base + l) * 512 + d * 256 + tid] = o4;
  }
}

// ---------------------------------------------------------------------------
extern "C" void kernel_launch(void* const* d_in, const int* in_sizes, int n_in,
                              void* d_out, int out_size, void* d_ws, size_t ws_size,
                              hipStream_t stream) {
  (void)in_sizes; (void)n_in; (void)out_size; (void)ws_size;
  const float* x  = (const float*)d_in[0];
  const float* fw = (const float*)d_in[1];
  const float* bw = (const float*)d_in[2];
  const float* ow = (const float*)d_in[3];
  float* out = (float*)d_out;
  char* ws = (char*)d_ws;

  u16* Zf  = (u16*)(ws + 0);                       //  64 MiB
  u16* Hf  = (u16*)(ws + 67108864ull);             //  64 MiB
  u16* Y   = (u16*)(ws + 134217728ull);            // 128 MiB
  u16* Xt  = (u16*)(ws + 134217728ull);            //  64 MiB (alias of Y)
  u16* W1n = (u16*)(ws + 268435456ull);            //   8 MiB
  u16* W2n = (u16*)(ws + 276824064ull);            //   4 MiB
  float* segA = (float*)(ws + 281018368ull);
  float* segB = (float*)(ws + 283115520ull);
  float* hin  = (float*)(ws + 285212672ull);
  u16* Zb = (u16*)d_out;
  u16* Hb = (u16*)((char*)d_out + 67108864ull);

  k_wnorm    <<<dim3(5120),      dim3(256), 0, stream>>>(fw, bw, ow, W1n, W2n);
  k_transpose<<<dim3(64, 16, 8), dim3(256), 0, stream>>>(x, Xt);
  gemm8p<1024, 32, 0><<<dim3(2048), dim3(512), 0, stream>>>(Xt, W1n, Zf, Hf, Zb, Hb, nullptr);
  k_scan_seg <<<dim3(NSEG, 1, 16), dim3(256), 0, stream>>>(Zf, Hf, Zb, Hb, segA, segB);
  k_scan_mid <<<dim3(16),        dim3(256), 0, stream>>>(segA, segB, hin);
  k_scan_fin <<<dim3(NSEG, 1, 16), dim3(256), 0, stream>>>(Zf, Hf, Zb, Hb, hin, Y);
  gemm8p<2048, 64, 1><<<dim3(512),  dim3(512), 0, stream>>>(W2n, Y, nullptr, nullptr, nullptr, nullptr, out);
}